// Round 3
// baseline (409.880 us; speedup 1.0000x reference)
//
#include <hip/hip_runtime.h>

// Problem constants (B=2, T=2048, C=1024, H=16, hd=64)
#define T_SEQ 2048
#define NH    16
#define HD    64
#define CDIM  1024
#define BDIM  2

using floatx4 = __attribute__((ext_vector_type(4))) float;
using bf16x8  = __attribute__((ext_vector_type(8))) __bf16;
typedef unsigned short u16;

__device__ __forceinline__ u16 f2bf(float f) {
  unsigned int u = __float_as_uint(f);
  u += 0x7fffu + ((u >> 16) & 1u);          // RNE
  return (u16)(u >> 16);
}
__device__ __forceinline__ float bf2f(u16 h) {
  return __uint_as_float(((unsigned int)h) << 16);
}
// async global->LDS, 16B/lane; LDS dest must be wave-uniform base + lane*16.
__device__ __forceinline__ void gld16(const void* g, const void* l) {
  __builtin_amdgcn_global_load_lds(
      (const __attribute__((address_space(1))) unsigned int*)(unsigned long long)g,
      (__attribute__((address_space(3))) unsigned int*)(unsigned int)(unsigned long long)l,
      16, 0, 0);
}

// ---------------- split cast fp32 -> bf16 hi/lo ----------------
__global__ __launch_bounds__(256) void cast_split(const float* __restrict__ in,
                                                  u16* __restrict__ hi, u16* __restrict__ lo, int n4) {
  int i = blockIdx.x * 256 + threadIdx.x;
  if (i < n4) {
    float4 v = ((const float4*)in)[i];
    ushort4 h, l;
    h.x = f2bf(v.x); l.x = f2bf(v.x - bf2f(h.x));
    h.y = f2bf(v.y); l.y = f2bf(v.y - bf2f(h.y));
    h.z = f2bf(v.z); l.z = f2bf(v.z - bf2f(h.z));
    h.w = f2bf(v.w); l.w = f2bf(v.w - bf2f(h.w));
    ((ushort4*)hi)[i] = h;
    ((ushort4*)lo)[i] = l;
  }
}

// ---------------- split cast + transpose: W(K,N) fp32 -> WT(N,K) bf16 hi/lo ----------------
__global__ __launch_bounds__(256) void transpose_split(const float* __restrict__ W,
                                                       u16* __restrict__ WTh, u16* __restrict__ WTl,
                                                       int K, int N) {
  __shared__ float tile[32][33];
  int n0 = blockIdx.x * 32, k0 = blockIdx.y * 32;
  int tx = threadIdx.x, ty = threadIdx.y;   // block (32,8)
#pragma unroll
  for (int i = 0; i < 32; i += 8)
    tile[ty + i][tx] = W[(size_t)(k0 + ty + i) * N + n0 + tx];
  __syncthreads();
#pragma unroll
  for (int i = 0; i < 32; i += 8) {
    float v = tile[tx][ty + i];
    u16 h = f2bf(v);
    WTh[(size_t)(n0 + ty + i) * K + k0 + tx] = h;
    WTl[(size_t)(n0 + ty + i) * K + k0 + tx] = f2bf(v - bf2f(h));
  }
}

// ---------------- split GEMM: C = A*B, A/B given as bf16 hi/lo pairs (near-fp32) ----------
// 3-term: Ah*Bh + Ah*Bl + Al*Bh. 128x128 tile, BK=32, 4 waves each 64x64.
// EPI=0: scatter QKV epilogue (q->out0, k->out1 as (BH,T,64) fp32; v->out2 (v_t output))
// EPI=1: plain fp32 C(M,N) -> out0
template <int EPI>
__global__ __launch_bounds__(256) void gemm_split(const u16* __restrict__ Ah, const u16* __restrict__ Al,
                                                  const u16* __restrict__ Bh, const u16* __restrict__ Bl,
                                                  float* __restrict__ out0, float* __restrict__ out1,
                                                  float* __restrict__ out2,
                                                  int M, int N, int K) {
  __shared__ u16 Ash[128 * 32], Asl[128 * 32];
  __shared__ u16 Bsh[128 * 32], Bsl[128 * 32];
  const int tid  = threadIdx.x;
  const int lane = tid & 63, wave = tid >> 6;
  const int quad = lane >> 4, l16 = lane & 15;
  const int wm = (wave & 1) * 64, wn = (wave >> 1) * 64;
  const int row0 = blockIdx.x * 128, col0 = blockIdx.y * 128;
  const int srow = tid >> 2;                       // staging row 0..63
  const int sc   = tid & 3;                        // chunk 0..3 (8 elems)
  const int sgc  = (sc ^ ((srow >> 1) & 3)) * 8;   // swizzled source chunk
  floatx4 acc[4][4] = {};
  for (int k0 = 0; k0 < K; k0 += 32) {
    __syncthreads();
    gld16(Ah + (size_t)(row0 + srow     ) * K + k0 + sgc, &Ash[srow * 32 + sc * 8]);
    gld16(Ah + (size_t)(row0 + srow + 64) * K + k0 + sgc, &Ash[(srow + 64) * 32 + sc * 8]);
    gld16(Al + (size_t)(row0 + srow     ) * K + k0 + sgc, &Asl[srow * 32 + sc * 8]);
    gld16(Al + (size_t)(row0 + srow + 64) * K + k0 + sgc, &Asl[(srow + 64) * 32 + sc * 8]);
    gld16(Bh + (size_t)(col0 + srow     ) * K + k0 + sgc, &Bsh[srow * 32 + sc * 8]);
    gld16(Bh + (size_t)(col0 + srow + 64) * K + k0 + sgc, &Bsh[(srow + 64) * 32 + sc * 8]);
    gld16(Bl + (size_t)(col0 + srow     ) * K + k0 + sgc, &Bsl[srow * 32 + sc * 8]);
    gld16(Bl + (size_t)(col0 + srow + 64) * K + k0 + sgc, &Bsl[(srow + 64) * 32 + sc * 8]);
    __syncthreads();
    bf16x8 ah[4], al[4], bh4[4], bl4[4];
#pragma unroll
    for (int mt = 0; mt < 4; mt++) {
      int r = wm + mt * 16 + l16;
      int co = (quad ^ ((r >> 1) & 3)) * 8;
      ah[mt] = *(const bf16x8*)&Ash[r * 32 + co];
      al[mt] = *(const bf16x8*)&Asl[r * 32 + co];
    }
#pragma unroll
    for (int nt = 0; nt < 4; nt++) {
      int r = wn + nt * 16 + l16;
      int co = (quad ^ ((r >> 1) & 3)) * 8;
      bh4[nt] = *(const bf16x8*)&Bsh[r * 32 + co];
      bl4[nt] = *(const bf16x8*)&Bsl[r * 32 + co];
    }
#pragma unroll
    for (int mt = 0; mt < 4; mt++)
#pragma unroll
      for (int nt = 0; nt < 4; nt++) {
        acc[mt][nt] = __builtin_amdgcn_mfma_f32_16x16x32_bf16(ah[mt], bh4[nt], acc[mt][nt], 0, 0, 0);
        acc[mt][nt] = __builtin_amdgcn_mfma_f32_16x16x32_bf16(ah[mt], bl4[nt], acc[mt][nt], 0, 0, 0);
        acc[mt][nt] = __builtin_amdgcn_mfma_f32_16x16x32_bf16(al[mt], bh4[nt], acc[mt][nt], 0, 0, 0);
      }
  }
  // C/D layout: col = lane&15, row = quad*4 + reg
#pragma unroll
  for (int mt = 0; mt < 4; mt++)
#pragma unroll
    for (int nt = 0; nt < 4; nt++) {
      int col = col0 + wn + nt * 16 + l16;
      if (EPI == 0) {
        int which = col >> 10;               // wave-uniform (16 | 1024)
        int h = (col >> 6) & 15, d = col & 63;
        float* dst = (which == 0) ? out0 : (which == 1) ? out1 : out2;
#pragma unroll
        for (int r = 0; r < 4; r++) {
          int row = row0 + wm + mt * 16 + quad * 4 + r;
          int b = row >> 11, t = row & 2047;
          dst[(((size_t)(b * NH + h)) * T_SEQ + t) * HD + d] = acc[mt][nt][r];
        }
      } else {
#pragma unroll
        for (int r = 0; r < 4; r++) {
          int row = row0 + wm + mt * 16 + quad * 4 + r;
          out0[(size_t)row * N + col] = acc[mt][nt][r];
        }
      }
    }
}

// ---------------- RoPE fp32 on fp32 q,k; emits hi/lo splits + k_t fp32 ----------------
__global__ __launch_bounds__(256) void rope_split(const float* __restrict__ qf,
                                                  const float* __restrict__ kf,
                                                  u16* __restrict__ qh, u16* __restrict__ ql_,
                                                  u16* __restrict__ kh, u16* __restrict__ kl_,
                                                  float* __restrict__ kt_out) {
  int gid = blockIdx.x * 4 + (threadIdx.x >> 6);  // bh*2048 + t
  int d   = threadIdx.x & 63;
  int t   = gid & (T_SEQ - 1);
  int i   = d & 31;
  size_t rb = (size_t)gid * 64;
  float q1 = qf[rb + 2 * i], q2 = qf[rb + 2 * i + 1];
  float k1 = kf[rb + 2 * i], k2 = kf[rb + 2 * i + 1];
  float inv = expf((float)i * -0.28782313662425572f);  // 10000^(-i/32)
  float ang = (float)t * inv;
  float sn = sinf(ang), cs = cosf(ang);
  float qv = (d < 32) ? (q1 * cs - q2 * sn) : (q1 * sn + q2 * cs);
  float kv = (d < 32) ? (k1 * cs - k2 * sn) : (k1 * sn + k2 * cs);
  float qs = qv * 0.125f;                   // fold softmax scale into q
  size_t o = rb + d;
  u16 h1 = f2bf(qs); qh[o] = h1; ql_[o] = f2bf(qs - bf2f(h1));
  u16 h2 = f2bf(kv); kh[o] = h2; kl_[o] = f2bf(kv - bf2f(h2));
  kt_out[o] = kv;
}

// ---------------- V^T pack: v_t fp32 (BH,T,64) -> vtb bf16 (BH,64,T) ----------------
__global__ __launch_bounds__(256) void v_pack_lite(const float* __restrict__ vt,
                                                   u16* __restrict__ vtb) {
  __shared__ float tile[64][65];
  int blk = blockIdx.x;
  int t0 = (blk & 31) * 64;
  int bh = blk >> 5;
  int tx = threadIdx.x & 63, ty = threadIdx.x >> 6;
#pragma unroll
  for (int i = ty; i < 64; i += 4)
    tile[i][tx] = vt[((size_t)bh * T_SEQ + t0 + i) * HD + tx];
  __syncthreads();
#pragma unroll
  for (int i = ty; i < 64; i += 4)
    vtb[((size_t)bh * HD + i) * T_SEQ + t0 + tx] = f2bf(tile[tx][i]);
}

// ---------------- fused causal flash attention (Q,K split; exact scores) ----------------
__global__ __launch_bounds__(256) void attn_fused(const u16* __restrict__ qh, const u16* __restrict__ ql_,
                                                  const u16* __restrict__ kh, const u16* __restrict__ kl_,
                                                  const u16* __restrict__ vtb,
                                                  u16* __restrict__ Oh, u16* __restrict__ Ol) {
  __shared__ u16 Qsh[128 * 64], Qsl[128 * 64];
  __shared__ u16 Ksh[128 * 64], Ksl[128 * 64];
  __shared__ u16 Vts[64 * 128];
  __shared__ u16 Ps[4][32 * 128];
  const int tid = threadIdx.x;
  const int lane = tid & 63, wave = tid >> 6;
  const int quad = lane >> 4, l16 = lane & 15;
  const int qt = blockIdx.x & 15;
  const int bh = blockIdx.x >> 4;
  const size_t qoff = ((size_t)bh * T_SEQ + qt * 128) * HD;
#pragma unroll
  for (int j = 0; j < 4; j++) {
    int t2 = j * 256 + tid;
    int r = t2 >> 3, c = t2 & 7;
    int go = r * HD + (c ^ (r & 7)) * 8;
    gld16(qh + qoff + go, &Qsh[t2 * 8]);
    gld16(ql_ + qoff + go, &Qsl[t2 * 8]);
  }
  floatx4 oacc[2][4] = {};
  float mrow[2][4], lrow[2][4];
#pragma unroll
  for (int mt = 0; mt < 2; mt++)
#pragma unroll
    for (int r = 0; r < 4; r++) { mrow[mt][r] = -1e30f; lrow[mt][r] = 0.f; }

  for (int kt = 0; kt <= qt; kt++) {
    __syncthreads();
    const size_t koff = ((size_t)bh * T_SEQ + kt * 128) * HD;
    const u16* Vg = vtb + (size_t)bh * HD * T_SEQ + kt * 128;
#pragma unroll
    for (int j = 0; j < 4; j++) {
      int t2 = j * 256 + tid;
      int r = t2 >> 3, c = t2 & 7;
      int go = r * HD + (c ^ (r & 7)) * 8;
      gld16(kh + koff + go, &Ksh[t2 * 8]);
      gld16(kl_ + koff + go, &Ksl[t2 * 8]);
    }
#pragma unroll
    for (int j = 0; j < 4; j++) {
      int t2 = j * 256 + tid;
      int r = t2 >> 4, c = t2 & 15;
      gld16(Vg + (size_t)r * T_SEQ + (c ^ (r & 15)) * 8, &Vts[t2 * 8]);
    }
    __syncthreads();

    // S = Q K^T (3-term split, fp32-precise)
    floatx4 sacc[2][8] = {};
#pragma unroll
    for (int ks = 0; ks < 2; ks++) {
      bf16x8 aqh[2], aql[2];
#pragma unroll
      for (int mt = 0; mt < 2; mt++) {
        int r = wave * 32 + mt * 16 + l16;
        int co = (((ks * 4 + quad) ^ (r & 7)) * 8);
        aqh[mt] = *(const bf16x8*)&Qsh[r * 64 + co];
        aql[mt] = *(const bf16x8*)&Qsl[r * 64 + co];
      }
#pragma unroll
      for (int nt = 0; nt < 8; nt++) {
        int r = nt * 16 + l16;
        int co = (((ks * 4 + quad) ^ (r & 7)) * 8);
        bf16x8 bkh = *(const bf16x8*)&Ksh[r * 64 + co];
        bf16x8 bkl = *(const bf16x8*)&Ksl[r * 64 + co];
#pragma unroll
        for (int mt = 0; mt < 2; mt++) {
          sacc[mt][nt] = __builtin_amdgcn_mfma_f32_16x16x32_bf16(aqh[mt], bkh, sacc[mt][nt], 0, 0, 0);
          sacc[mt][nt] = __builtin_amdgcn_mfma_f32_16x16x32_bf16(aqh[mt], bkl, sacc[mt][nt], 0, 0, 0);
          sacc[mt][nt] = __builtin_amdgcn_mfma_f32_16x16x32_bf16(aql[mt], bkh, sacc[mt][nt], 0, 0, 0);
        }
      }
    }
    if (kt == qt) {                          // diagonal: causal mask
#pragma unroll
      for (int mt = 0; mt < 2; mt++)
#pragma unroll
        for (int nt = 0; nt < 8; nt++)
#pragma unroll
          for (int r = 0; r < 4; r++) {
            int trow = wave * 32 + mt * 16 + quad * 4 + r;
            int scol = nt * 16 + l16;
            if (scol > trow) sacc[mt][nt][r] = -1e30f;
          }
    }
    // online softmax (row across 16 lanes)
#pragma unroll
    for (int mt = 0; mt < 2; mt++)
#pragma unroll
      for (int r = 0; r < 4; r++) {
        float mx = sacc[mt][0][r];
#pragma unroll
        for (int nt = 1; nt < 8; nt++) mx = fmaxf(mx, sacc[mt][nt][r]);
#pragma unroll
        for (int off = 1; off < 16; off <<= 1) mx = fmaxf(mx, __shfl_xor(mx, off));
        float mnew = fmaxf(mrow[mt][r], mx);
        float alpha = __expf(mrow[mt][r] - mnew);
        mrow[mt][r] = mnew;
        float rs = 0.f;
#pragma unroll
        for (int nt = 0; nt < 8; nt++) {
          float p = __expf(sacc[mt][nt][r] - mnew);
          sacc[mt][nt][r] = p;
          rs += p;
        }
#pragma unroll
        for (int off = 1; off < 16; off <<= 1) rs += __shfl_xor(rs, off);
        lrow[mt][r] = lrow[mt][r] * alpha + rs;
        // rescale O accumulator — ONLY component r (row quad*4+r)!
#pragma unroll
        for (int ntv = 0; ntv < 4; ntv++) oacc[mt][ntv][r] *= alpha;
      }
    // P: C-layout regs -> LDS -> A-layout
    u16* Pw = Ps[wave];
#pragma unroll
    for (int mt = 0; mt < 2; mt++)
#pragma unroll
      for (int nt = 0; nt < 8; nt++)
#pragma unroll
        for (int r = 0; r < 4; r++) {
          int row = mt * 16 + quad * 4 + r;
          int col = nt * 16 + l16;
          int slot = (col >> 3) ^ (row & 15);
          Pw[row * 128 + slot * 8 + (col & 7)] = f2bf(sacc[mt][nt][r]);
        }
    // O += P * V
#pragma unroll
    for (int ks = 0; ks < 4; ks++) {
      bf16x8 ap[2];
#pragma unroll
      for (int mt = 0; mt < 2; mt++) {
        int row = mt * 16 + l16;
        ap[mt] = *(const bf16x8*)&Pw[row * 128 + (((ks * 4 + quad) ^ (row & 15)) * 8)];
      }
#pragma unroll
      for (int ntv = 0; ntv < 4; ntv++) {
        int row = ntv * 16 + l16;
        bf16x8 bv = *(const bf16x8*)&Vts[row * 128 + (((ks * 4 + quad) ^ (row & 15)) * 8)];
#pragma unroll
        for (int mt = 0; mt < 2; mt++)
          oacc[mt][ntv] = __builtin_amdgcn_mfma_f32_16x16x32_bf16(ap[mt], bv, oacc[mt][ntv], 0, 0, 0);
      }
    }
  }
  // epilogue: O /= l, split hi/lo for out-proj; layout (B,T,C)
  const int b = bh >> 4, h = bh & 15;
#pragma unroll
  for (int mt = 0; mt < 2; mt++)
#pragma unroll
    for (int r = 0; r < 4; r++) {
      float invl = 1.f / lrow[mt][r];
      int trow = qt * 128 + wave * 32 + mt * 16 + quad * 4 + r;
#pragma unroll
      for (int ntv = 0; ntv < 4; ntv++) {
        int d = ntv * 16 + l16;
        float ov = oacc[mt][ntv][r] * invl;
        size_t o = ((size_t)(b * T_SEQ) + trow) * CDIM + h * HD + d;
        u16 hh = f2bf(ov);
        Oh[o] = hh;
        Ol[o] = f2bf(ov - bf2f(hh));
      }
    }
}

extern "C" void kernel_launch(void* const* d_in, const int* in_sizes, int n_in,
                              void* d_out, int out_size, void* d_ws, size_t ws_size,
                              hipStream_t stream) {
  const float* x     = (const float*)d_in[0];
  const float* w_qkv = (const float*)d_in[2];
  const float* w_out = (const float*)d_in[3];
  float* out    = (float*)d_out;                       // (B,T,C) fp32
  float* kt_out = out + (size_t)BDIM * T_SEQ * CDIM;   // (B,H,T,64) fp32
  float* vt_out = kt_out + (size_t)BDIM * T_SEQ * CDIM;

  const size_t F = (size_t)4194304;   // 4M elements (4096x1024)
  char* base = (char*)d_ws;
  // [0, 2F*4): qf, kf fp32 — gemm_qkv -> rope, then dead
  float* qf = (float*)base;
  float* kf = qf + F;
  char* r1 = base + 2 * F * 4;        // 33.55MB offset
  // r1 first: xh,xl (F u16 each), wqh,wql (3M u16 each) — dead after gemm_qkv
  u16* xh  = (u16*)r1;
  u16* xl  = xh + F;
  u16* wqh = xl + F;
  u16* wql = wqh + (size_t)3145728;
  // r1 reuse (rope outputs): qh,ql,kh,kl (F u16 each = 33.55MB)
  u16* qhh = (u16*)r1;
  u16* qll = qhh + F;
  u16* khh = qll + F;
  u16* kll = khh + F;
  char* r2 = r1 + 4 * F * 2;          // 67.1MB offset
  u16* woh = (u16*)r2;
  u16* wol = woh + (size_t)1048576;   // ends at 71.3MB
  // qf/kf region reuse (after rope): vtb, Oh, Ol
  u16* vtb = (u16*)base;              // F u16
  u16* Oh  = (u16*)(base + F * 2);
  u16* Ol  = Oh + F;

  cast_split<<<4096, 256, 0, stream>>>(x, xh, xl, 1048576);
  transpose_split<<<dim3(96, 32), dim3(32, 8), 0, stream>>>(w_qkv, wqh, wql, 1024, 3072);
  transpose_split<<<dim3(32, 32), dim3(32, 8), 0, stream>>>(w_out, woh, wol, 1024, 1024);
  gemm_split<0><<<dim3(32, 24), 256, 0, stream>>>(xh, xl, wqh, wql, qf, kf, vt_out, 4096, 3072, 1024);
  rope_split<<<16384, 256, 0, stream>>>(qf, kf, qhh, qll, khh, kll, kt_out);
  v_pack_lite<<<1024, 256, 0, stream>>>(vt_out, vtb);
  attn_fused<<<512, 256, 0, stream>>>(qhh, qll, khh, kll, vtb, Oh, Ol);
  gemm_split<1><<<dim3(32, 8), 256, 0, stream>>>(Oh, Ol, woh, wol, out, nullptr, nullptr, 4096, 1024, 1024);
}

// Round 4
// 286.521 us; speedup vs baseline: 1.4305x; 1.4305x over previous
//
#include <hip/hip_runtime.h>

// Problem constants (B=2, T=2048, C=1024, H=16, hd=64)
#define T_SEQ 2048
#define NH    16
#define HD    64
#define CDIM  1024
#define BDIM  2

using floatx4 = __attribute__((ext_vector_type(4))) float;
using bf16x8  = __attribute__((ext_vector_type(8))) __bf16;
using half4   = __attribute__((ext_vector_type(4))) _Float16;
typedef unsigned short u16;

__device__ __forceinline__ u16 f2bf(float f) {
  unsigned int u = __float_as_uint(f);
  u += 0x7fffu + ((u >> 16) & 1u);          // RNE
  return (u16)(u >> 16);
}
__device__ __forceinline__ float bf2f(u16 h) {
  return __uint_as_float(((unsigned int)h) << 16);
}
__device__ __forceinline__ u16 f2h(float f) {
  union { _Float16 h; u16 u; } c; c.h = (_Float16)f; return c.u;
}
// async global->LDS, 16B/lane; LDS dest must be wave-uniform base + lane*16.
__device__ __forceinline__ void gld16(const void* g, const void* l) {
  __builtin_amdgcn_global_load_lds(
      (const __attribute__((address_space(1))) unsigned int*)(unsigned long long)g,
      (__attribute__((address_space(3))) unsigned int*)(unsigned int)(unsigned long long)l,
      16, 0, 0);
}

// ---------------- cast fp32 -> bf16 ----------------
__global__ __launch_bounds__(256) void cast_bf16(const float* __restrict__ in,
                                                 u16* __restrict__ out, int n4) {
  int i = blockIdx.x * 256 + threadIdx.x;
  if (i < n4) {
    float4 v = ((const float4*)in)[i];
    ushort4 o;
    o.x = f2bf(v.x); o.y = f2bf(v.y); o.z = f2bf(v.z); o.w = f2bf(v.w);
    ((ushort4*)out)[i] = o;
  }
}

// ---------------- cast + transpose weights: W(K,N) fp32 -> WT(N,K) bf16 ----------------
__global__ __launch_bounds__(256) void transpose_cast(const float* __restrict__ W,
                                                      u16* __restrict__ WT,
                                                      int K, int N) {
  __shared__ float tile[32][33];
  int n0 = blockIdx.x * 32, k0 = blockIdx.y * 32;
  int tx = threadIdx.x, ty = threadIdx.y;   // block (32,8)
#pragma unroll
  for (int i = 0; i < 32; i += 8)
    tile[ty + i][tx] = W[(size_t)(k0 + ty + i) * N + n0 + tx];
  __syncthreads();
#pragma unroll
  for (int i = 0; i < 32; i += 8)
    WT[(size_t)(n0 + ty + i) * K + k0 + tx] = f2bf(tile[tx][ty + i]);
}

// ---------------- single-bf16 GEMM (m97 structure): C(M,N) = A(M,K)*BT(N,K)^T ----------
template <bool OUT_F32>
__global__ __launch_bounds__(256) void gemm_bt(const u16* __restrict__ A,
                                               const u16* __restrict__ BT,
                                               float* __restrict__ Cf,
                                               u16* __restrict__ Cb,
                                               int M, int N, int K) {
  __shared__ u16 As[128 * 32];
  __shared__ u16 Bs[128 * 32];
  const int tid  = threadIdx.x;
  const int lane = tid & 63, wave = tid >> 6;
  const int quad = lane >> 4, l16 = lane & 15;
  const int wm = (wave & 1) * 64, wn = (wave >> 1) * 64;
  const int row0 = blockIdx.x * 128, col0 = blockIdx.y * 128;
  const int srow = tid >> 2;                       // staging row 0..63
  const int sc   = tid & 3;                        // chunk 0..3 (8 elems)
  const int sgc  = (sc ^ ((srow >> 1) & 3)) * 8;   // swizzled source chunk
  floatx4 acc[4][4] = {};
  for (int k0 = 0; k0 < K; k0 += 32) {
    __syncthreads();
    gld16(A  + (size_t)(row0 + srow     ) * K + k0 + sgc, &As[srow * 32 + sc * 8]);
    gld16(A  + (size_t)(row0 + srow + 64) * K + k0 + sgc, &As[(srow + 64) * 32 + sc * 8]);
    gld16(BT + (size_t)(col0 + srow     ) * K + k0 + sgc, &Bs[srow * 32 + sc * 8]);
    gld16(BT + (size_t)(col0 + srow + 64) * K + k0 + sgc, &Bs[(srow + 64) * 32 + sc * 8]);
    __syncthreads();
    bf16x8 af[4], bfv[4];
#pragma unroll
    for (int mt = 0; mt < 4; mt++) {
      int r = wm + mt * 16 + l16;
      af[mt] = *(const bf16x8*)&As[r * 32 + (quad ^ ((r >> 1) & 3)) * 8];
    }
#pragma unroll
    for (int nt = 0; nt < 4; nt++) {
      int r = wn + nt * 16 + l16;
      bfv[nt] = *(const bf16x8*)&Bs[r * 32 + (quad ^ ((r >> 1) & 3)) * 8];
    }
#pragma unroll
    for (int mt = 0; mt < 4; mt++)
#pragma unroll
      for (int nt = 0; nt < 4; nt++)
        acc[mt][nt] = __builtin_amdgcn_mfma_f32_16x16x32_bf16(af[mt], bfv[nt], acc[mt][nt], 0, 0, 0);
  }
  // C/D layout: col = lane&15, row = quad*4 + reg
#pragma unroll
  for (int mt = 0; mt < 4; mt++)
#pragma unroll
    for (int nt = 0; nt < 4; nt++)
#pragma unroll
      for (int r = 0; r < 4; r++) {
        int row = row0 + wm + mt * 16 + quad * 4 + r;
        int col = col0 + wn + nt * 16 + l16;
        float v = acc[mt][nt][r];
        if (OUT_F32) Cf[(size_t)row * N + col] = v;
        else         Cb[(size_t)row * N + col] = f2bf(v);
      }
}

// ---------------- RoPE: qkv bf16 -> q f16 (scaled 0.125*log2e), k f16, k_t fp32 ----------
__global__ __launch_bounds__(256) void rope_qk(const u16* __restrict__ qkv,
                                               u16* __restrict__ qf16,
                                               u16* __restrict__ kf16,
                                               float* __restrict__ kt_out) {
  int gid = blockIdx.x * 4 + (threadIdx.x >> 6);  // (b,h,t) row index
  int d   = threadIdx.x & 63;
  int t   = gid & (T_SEQ - 1);
  int h   = (gid >> 11) & 15;
  int b   = gid >> 15;
  const u16* qrow = qkv + ((size_t)(b * T_SEQ + t)) * 3072 + h * 64;
  int i = d & 31;
  unsigned int qp = *(const unsigned int*)(qrow + 2 * i);
  unsigned int kp = *(const unsigned int*)(qrow + 1024 + 2 * i);
  float q1 = bf2f((u16)qp), q2 = bf2f((u16)(qp >> 16));
  float k1 = bf2f((u16)kp), k2 = bf2f((u16)(kp >> 16));
  float inv = expf((float)i * -0.28782313662425572f);  // 10000^(-i/32)
  float ang = (float)t * inv;
  float sn = sinf(ang), cs = cosf(ang);
  float qv = (d < 32) ? (q1 * cs - q2 * sn) : (q1 * sn + q2 * cs);
  float kv = (d < 32) ? (k1 * cs - k2 * sn) : (k1 * sn + k2 * cs);
  size_t o = (size_t)gid * 64 + d;
  qf16[o] = f2h(qv * 0.18033688011112042f);   // 0.125 * log2(e): base-2 softmax
  kf16[o] = f2h(kv);
  kt_out[o] = kv;
}

// ---------------- V: v_t fp32 output + V^T f16 (BH,64,T) ----------------
__global__ __launch_bounds__(256) void v_pack(const u16* __restrict__ qkv,
                                              float* __restrict__ vt_out,
                                              u16* __restrict__ vtf) {
  __shared__ float tile[64][65];
  int blk = blockIdx.x;
  int t0 = (blk & 31) * 64;                 // T/64 = 32
  int bh = blk >> 5;
  int b = bh >> 4, h = bh & 15;
  int tx = threadIdx.x & 63, ty = threadIdx.x >> 6;
#pragma unroll
  for (int i = ty; i < 64; i += 4) {
    float v = bf2f(qkv[((size_t)(b * T_SEQ + t0 + i)) * 3072 + 2048 + h * 64 + tx]);
    tile[i][tx] = v;
    vt_out[((size_t)bh * T_SEQ + t0 + i) * 64 + tx] = v;
  }
  __syncthreads();
#pragma unroll
  for (int i = ty; i < 64; i += 4)
    vtf[((size_t)bh * 64 + i) * T_SEQ + t0 + tx] = f2h(tile[tx][i]);
}

// ---------------- fused causal flash attention, S^T orientation, all 16x16x16 f16 -------
// Per block: one 128-row Q tile of one head. 4 waves; wave w owns t-columns [w*32,w*32+32).
// S^T = K·Q^T : MFMA C-layout (s=quad*4+r, t=lane&15) == B-operand layout of 16x16x16
// => P feeds PV (O^T = V^T·P^T) directly from registers, no LDS round-trip.
__global__ __launch_bounds__(256) void attn_fused(const u16* __restrict__ qf16,
                                                  const u16* __restrict__ kf16,
                                                  const u16* __restrict__ vtf,
                                                  u16* __restrict__ Ob) {
  __shared__ u16 Ks[128 * 64];              // K tile (s,d) f16, chunk-swizzled (also Q stage)
  __shared__ u16 Vts[64 * 128];             // V^T tile (d,s) f16, chunk-swizzled
  const int tid = threadIdx.x;
  const int lane = tid & 63, wave = tid >> 6;
  const int quad = lane >> 4, l16 = lane & 15;
  const int qh2 = quad >> 1, ql2 = (quad & 1) * 4;  // frag sub-chunk addressing
  const int qt = blockIdx.x & 15;
  const int bh = blockIdx.x >> 4;

  // --- stage Q through Ks, hold B-operand frags in registers ---
  const u16* Qg = qf16 + ((size_t)bh * T_SEQ + qt * 128) * HD;
#pragma unroll
  for (int j = 0; j < 4; j++) {
    int t2 = j * 256 + tid;
    int r = t2 >> 3, c = t2 & 7;
    gld16(Qg + r * HD + (c ^ (r & 7)) * 8, &Ks[t2 * 8]);
  }
  __syncthreads();
  half4 qfrag[2][4];                        // [tt][kc]: B[k=d][n=t], k=quad*4+j
#pragma unroll
  for (int tt = 0; tt < 2; tt++) {
    int trow = wave * 32 + tt * 16 + l16;
#pragma unroll
    for (int kc = 0; kc < 4; kc++)
      qfrag[tt][kc] = *(const half4*)&Ks[trow * 64 + (((kc * 2 + qh2) ^ (trow & 7)) * 8) + ql2];
  }

  floatx4 oacc[4][2] = {};                  // O^T tiles [dt][tt]
  float mrow[2] = {-1e30f, -1e30f}, lrow[2] = {0.f, 0.f};

  for (int kt = 0; kt <= qt; kt++) {
    __syncthreads();                        // prev compute done (and initial qfrag reads)
    const size_t koff = ((size_t)bh * T_SEQ + kt * 128) * HD;
    const u16* Vg = vtf + (size_t)bh * HD * T_SEQ + kt * 128;
#pragma unroll
    for (int j = 0; j < 4; j++) {
      int t2 = j * 256 + tid;
      int r = t2 >> 3, c = t2 & 7;
      gld16(kf16 + koff + r * HD + (c ^ (r & 7)) * 8, &Ks[t2 * 8]);
    }
#pragma unroll
    for (int j = 0; j < 4; j++) {
      int t2 = j * 256 + tid;
      int r = t2 >> 4, c = t2 & 15;
      gld16(Vg + (size_t)r * T_SEQ + (c ^ (r & 15)) * 8, &Vts[t2 * 8]);
    }
    __syncthreads();                        // staging landed

    // S^T = K·Q^T : A=K (m=s), B=Q^T frags
    floatx4 sacc[8][2] = {};
#pragma unroll
    for (int kc = 0; kc < 4; kc++)
#pragma unroll
      for (int st = 0; st < 8; st++) {
        int srow = st * 16 + l16;
        half4 ak = *(const half4*)&Ks[srow * 64 + (((kc * 2 + qh2) ^ (srow & 7)) * 8) + ql2];
#pragma unroll
        for (int tt = 0; tt < 2; tt++)
          sacc[st][tt] = __builtin_amdgcn_mfma_f32_16x16x16f16(ak, qfrag[tt][kc], sacc[st][tt], 0, 0, 0);
      }
    if (kt == qt) {                         // diagonal tile: causal mask s<=t (tile-local)
#pragma unroll
      for (int tt = 0; tt < 2; tt++) {
        int tl = wave * 32 + tt * 16 + l16;
#pragma unroll
        for (int st = 0; st < 8; st++)
#pragma unroll
          for (int r = 0; r < 4; r++)
            if (st * 16 + quad * 4 + r > tl) sacc[st][tt][r] = -1e30f;
      }
    }
    // online softmax per t-column (base-2; scale folded into q)
#pragma unroll
    for (int tt = 0; tt < 2; tt++) {
      floatx4 vm = sacc[0][tt];
#pragma unroll
      for (int st = 1; st < 8; st++) {
        vm[0] = fmaxf(vm[0], sacc[st][tt][0]); vm[1] = fmaxf(vm[1], sacc[st][tt][1]);
        vm[2] = fmaxf(vm[2], sacc[st][tt][2]); vm[3] = fmaxf(vm[3], sacc[st][tt][3]);
      }
      float mx = fmaxf(fmaxf(vm[0], vm[1]), fmaxf(vm[2], vm[3]));
      mx = fmaxf(mx, __shfl_xor(mx, 16));
      mx = fmaxf(mx, __shfl_xor(mx, 32));
      float mnew = fmaxf(mrow[tt], mx);
      float alpha = exp2f(mrow[tt] - mnew);
      mrow[tt] = mnew;
      floatx4 vs = {0.f, 0.f, 0.f, 0.f};
#pragma unroll
      for (int st = 0; st < 8; st++) {
#pragma unroll
        for (int r = 0; r < 4; r++) sacc[st][tt][r] = exp2f(sacc[st][tt][r] - mnew);
        vs += sacc[st][tt];
      }
      float rs = (vs[0] + vs[1]) + (vs[2] + vs[3]);
      rs += __shfl_xor(rs, 16);
      rs += __shfl_xor(rs, 32);
      lrow[tt] = lrow[tt] * alpha + rs;
#pragma unroll
      for (int dt = 0; dt < 4; dt++) oacc[dt][tt] *= alpha;   // alpha lane-uniform per tt
    }
    // O^T += V^T · P^T : P^T B-frags come straight from sacc registers
#pragma unroll
    for (int st = 0; st < 8; st++) {
      half4 bp[2];
#pragma unroll
      for (int tt = 0; tt < 2; tt++) {
        bp[tt][0] = (_Float16)sacc[st][tt][0]; bp[tt][1] = (_Float16)sacc[st][tt][1];
        bp[tt][2] = (_Float16)sacc[st][tt][2]; bp[tt][3] = (_Float16)sacc[st][tt][3];
      }
#pragma unroll
      for (int dt = 0; dt < 4; dt++) {
        int drow = dt * 16 + l16;
        half4 av = *(const half4*)&Vts[drow * 128 + (((st * 2 + qh2) ^ (drow & 15)) * 8) + ql2];
#pragma unroll
        for (int tt = 0; tt < 2; tt++)
          oacc[dt][tt] = __builtin_amdgcn_mfma_f32_16x16x16f16(av, bp[tt], oacc[dt][tt], 0, 0, 0);
      }
    }
  }
  // epilogue: O[t][d] = oacc^T / l ; write bf16 (B,T,C)
  const int b = bh >> 4, h = bh & 15;
#pragma unroll
  for (int tt = 0; tt < 2; tt++) {
    int t = qt * 128 + wave * 32 + tt * 16 + l16;
    float invl = 1.f / lrow[tt];
#pragma unroll
    for (int dt = 0; dt < 4; dt++) {
      int d0 = dt * 16 + quad * 4;
      ushort4 o;
      o.x = f2bf(oacc[dt][tt][0] * invl);
      o.y = f2bf(oacc[dt][tt][1] * invl);
      o.z = f2bf(oacc[dt][tt][2] * invl);
      o.w = f2bf(oacc[dt][tt][3] * invl);
      *(ushort4*)&Ob[((size_t)(b * T_SEQ) + t) * CDIM + h * HD + d0] = o;
    }
  }
}

extern "C" void kernel_launch(void* const* d_in, const int* in_sizes, int n_in,
                              void* d_out, int out_size, void* d_ws, size_t ws_size,
                              hipStream_t stream) {
  const float* x     = (const float*)d_in[0];
  const float* w_qkv = (const float*)d_in[2];
  const float* w_out = (const float*)d_in[3];
  float* out    = (float*)d_out;                       // (B,T,C) fp32
  float* kt_out = out + (size_t)BDIM * T_SEQ * CDIM;   // (B,H,T,64) fp32
  float* vt_out = kt_out + (size_t)BDIM * T_SEQ * CDIM;

  // workspace layout (64 MB, with aliasing)
  const size_t F = (size_t)4194304;     // 4M elems = 4096x1024
  char* base = (char*)d_ws;
  u16* xb   = (u16*)base;                        // [0,8M)   dead after gemm_qkv
  u16* wqT  = xb + F;                            // [8,14M)  dead after gemm_qkv
  u16* woT  = wqT + (size_t)3145728;             // [14,16M) lives to end
  u16* qkvb = woT + (size_t)1048576;             // [16,40M) dead after v_pack
  u16* qf16 = qkvb + (size_t)3 * F;              // [40,48M)
  u16* kf16 = qf16 + F;                          // [48,56M)
  u16* vtf  = (u16*)base;                        // alias xb  [0,8M)
  u16* Ob   = kf16 + F;                          // [56,64M)

  cast_bf16<<<4096, 256, 0, stream>>>(x, xb, 1048576);
  transpose_cast<<<dim3(96, 32), dim3(32, 8), 0, stream>>>(w_qkv, wqT, 1024, 3072);
  transpose_cast<<<dim3(32, 32), dim3(32, 8), 0, stream>>>(w_out, woT, 1024, 1024);
  gemm_bt<false><<<dim3(32, 24), 256, 0, stream>>>(xb, wqT, (float*)nullptr, qkvb, 4096, 3072, 1024);
  rope_qk<<<16384, 256, 0, stream>>>(qkvb, qf16, kf16, kt_out);
  v_pack<<<1024, 256, 0, stream>>>(qkvb, vt_out, vtf);
  attn_fused<<<512, 256, 0, stream>>>(qf16, kf16, vtf, Ob);
  gemm_bt<true><<<dim3(32, 8), 256, 0, stream>>>(Ob, woT, out, (u16*)nullptr, 4096, 1024, 1024);
}

// Round 6
// 234.230 us; speedup vs baseline: 1.7499x; 1.2232x over previous
//
#include <hip/hip_runtime.h>

// Problem constants (B=2, T=2048, C=1024, H=16, hd=64)
#define T_SEQ 2048
#define NH    16
#define HD    64
#define CDIM  1024
#define BDIM  2

using floatx4 = __attribute__((ext_vector_type(4))) float;
using bf16x8  = __attribute__((ext_vector_type(8))) __bf16;
using half4   = __attribute__((ext_vector_type(4))) _Float16;
typedef unsigned short u16;

__device__ __forceinline__ u16 f2bf(float f) {
  unsigned int u = __float_as_uint(f);
  u += 0x7fffu + ((u >> 16) & 1u);          // RNE
  return (u16)(u >> 16);
}
__device__ __forceinline__ float bf2f(u16 h) {
  return __uint_as_float(((unsigned int)h) << 16);
}
__device__ __forceinline__ u16 f2h(float f) {
  union { _Float16 h; u16 u; } c; c.h = (_Float16)f; return c.u;
}
// packed f32x2 -> f16x2 (RTZ); bit_cast to unsigned for type-compat
__device__ __forceinline__ unsigned pk2h(float a, float b) {
  return __builtin_bit_cast(unsigned, __builtin_amdgcn_cvt_pkrtz(a, b));
}
// async global->LDS, 16B/lane; LDS dest must be wave-uniform base + lane*16.
__device__ __forceinline__ void gld16(const void* g, const void* l) {
  __builtin_amdgcn_global_load_lds(
      (const __attribute__((address_space(1))) unsigned int*)(unsigned long long)g,
      (__attribute__((address_space(3))) unsigned int*)(unsigned int)(unsigned long long)l,
      16, 0, 0);
}

// ---------------- cast fp32 -> bf16 ----------------
__global__ __launch_bounds__(256) void cast_bf16(const float* __restrict__ in,
                                                 u16* __restrict__ out, int n4) {
  int i = blockIdx.x * 256 + threadIdx.x;
  if (i < n4) {
    float4 v = ((const float4*)in)[i];
    ushort4 o;
    o.x = f2bf(v.x); o.y = f2bf(v.y); o.z = f2bf(v.z); o.w = f2bf(v.w);
    ((ushort4*)out)[i] = o;
  }
}

// ---------------- cast + transpose weights: W(K,N) fp32 -> WT(N,K) bf16 ----------------
__global__ __launch_bounds__(256) void transpose_cast(const float* __restrict__ W,
                                                      u16* __restrict__ WT,
                                                      int K, int N) {
  __shared__ float tile[32][33];
  int n0 = blockIdx.x * 32, k0 = blockIdx.y * 32;
  int tx = threadIdx.x, ty = threadIdx.y;   // block (32,8)
#pragma unroll
  for (int i = 0; i < 32; i += 8)
    tile[ty + i][tx] = W[(size_t)(k0 + ty + i) * N + n0 + tx];
  __syncthreads();
#pragma unroll
  for (int i = 0; i < 32; i += 8)
    WT[(size_t)(n0 + ty + i) * K + k0 + tx] = f2bf(tile[tx][ty + i]);
}

// ---------------- single-bf16 GEMM (m97 structure): C(M,N) = A(M,K)*BT(N,K)^T ----------
template <bool OUT_F32>
__global__ __launch_bounds__(256) void gemm_bt(const u16* __restrict__ A,
                                               const u16* __restrict__ BT,
                                               float* __restrict__ Cf,
                                               u16* __restrict__ Cb,
                                               int M, int N, int K) {
  __shared__ u16 As[128 * 32];
  __shared__ u16 Bs[128 * 32];
  const int tid  = threadIdx.x;
  const int lane = tid & 63, wave = tid >> 6;
  const int quad = lane >> 4, l16 = lane & 15;
  const int wm = (wave & 1) * 64, wn = (wave >> 1) * 64;
  const int row0 = blockIdx.x * 128, col0 = blockIdx.y * 128;
  const int srow = tid >> 2;                       // staging row 0..63
  const int sc   = tid & 3;                        // chunk 0..3 (8 elems)
  const int sgc  = (sc ^ ((srow >> 1) & 3)) * 8;   // swizzled source chunk
  floatx4 acc[4][4] = {};
  for (int k0 = 0; k0 < K; k0 += 32) {
    __syncthreads();
    gld16(A  + (size_t)(row0 + srow     ) * K + k0 + sgc, &As[srow * 32 + sc * 8]);
    gld16(A  + (size_t)(row0 + srow + 64) * K + k0 + sgc, &As[(srow + 64) * 32 + sc * 8]);
    gld16(BT + (size_t)(col0 + srow     ) * K + k0 + sgc, &Bs[srow * 32 + sc * 8]);
    gld16(BT + (size_t)(col0 + srow + 64) * K + k0 + sgc, &Bs[(srow + 64) * 32 + sc * 8]);
    __syncthreads();
    bf16x8 af[4], bfv[4];
#pragma unroll
    for (int mt = 0; mt < 4; mt++) {
      int r = wm + mt * 16 + l16;
      af[mt] = *(const bf16x8*)&As[r * 32 + (quad ^ ((r >> 1) & 3)) * 8];
    }
#pragma unroll
    for (int nt = 0; nt < 4; nt++) {
      int r = wn + nt * 16 + l16;
      bfv[nt] = *(const bf16x8*)&Bs[r * 32 + (quad ^ ((r >> 1) & 3)) * 8];
    }
#pragma unroll
    for (int mt = 0; mt < 4; mt++)
#pragma unroll
      for (int nt = 0; nt < 4; nt++)
        acc[mt][nt] = __builtin_amdgcn_mfma_f32_16x16x32_bf16(af[mt], bfv[nt], acc[mt][nt], 0, 0, 0);
  }
  // C/D layout: col = lane&15, row = quad*4 + reg
#pragma unroll
  for (int mt = 0; mt < 4; mt++)
#pragma unroll
    for (int nt = 0; nt < 4; nt++)
#pragma unroll
      for (int r = 0; r < 4; r++) {
        int row = row0 + wm + mt * 16 + quad * 4 + r;
        int col = col0 + wn + nt * 16 + l16;
        float v = acc[mt][nt][r];
        if (OUT_F32) Cf[(size_t)row * N + col] = v;
        else         Cb[(size_t)row * N + col] = f2bf(v);
      }
}

// ---------------- RoPE: qkv bf16 -> q f16 (scaled 0.125*log2e), k f16, k_t fp32 ----------
__global__ __launch_bounds__(256) void rope_qk(const u16* __restrict__ qkv,
                                               u16* __restrict__ qf16,
                                               u16* __restrict__ kf16,
                                               float* __restrict__ kt_out) {
  int gid = blockIdx.x * 4 + (threadIdx.x >> 6);  // (b,h,t) row index
  int d   = threadIdx.x & 63;
  int t   = gid & (T_SEQ - 1);
  int h   = (gid >> 11) & 15;
  int b   = gid >> 15;
  const u16* qrow = qkv + ((size_t)(b * T_SEQ + t)) * 3072 + h * 64;
  int i = d & 31;
  unsigned int qp = *(const unsigned int*)(qrow + 2 * i);
  unsigned int kp = *(const unsigned int*)(qrow + 1024 + 2 * i);
  float q1 = bf2f((u16)qp), q2 = bf2f((u16)(qp >> 16));
  float k1 = bf2f((u16)kp), k2 = bf2f((u16)(kp >> 16));
  float inv = expf((float)i * -0.28782313662425572f);  // 10000^(-i/32)
  float ang = (float)t * inv;
  float sn = sinf(ang), cs = cosf(ang);
  float qv = (d < 32) ? (q1 * cs - q2 * sn) : (q1 * sn + q2 * cs);
  float kv = (d < 32) ? (k1 * cs - k2 * sn) : (k1 * sn + k2 * cs);
  size_t o = (size_t)gid * 64 + d;
  qf16[o] = f2h(qv * 0.18033688011112042f);   // 0.125 * log2(e): base-2 softmax
  kf16[o] = f2h(kv);
  kt_out[o] = kv;
}

// ---------------- V: v_t fp32 output + V^T f16 (BH,64,T) ----------------
__global__ __launch_bounds__(256) void v_pack(const u16* __restrict__ qkv,
                                              float* __restrict__ vt_out,
                                              u16* __restrict__ vtf) {
  __shared__ float tile[64][65];
  int blk = blockIdx.x;
  int t0 = (blk & 31) * 64;                 // T/64 = 32
  int bh = blk >> 5;
  int b = bh >> 4, h = bh & 15;
  int tx = threadIdx.x & 63, ty = threadIdx.x >> 6;
#pragma unroll
  for (int i = ty; i < 64; i += 4) {
    float v = bf2f(qkv[((size_t)(b * T_SEQ + t0 + i)) * 3072 + 2048 + h * 64 + tx]);
    tile[i][tx] = v;
    vt_out[((size_t)bh * T_SEQ + t0 + i) * 64 + tx] = v;
  }
  __syncthreads();
#pragma unroll
  for (int i = ty; i < 64; i += 4)
    vtf[((size_t)bh * 64 + i) * T_SEQ + t0 + tx] = f2h(tile[tx][i]);
}

// ---------------- fused causal flash attention, S^T orientation, 16x16x16 f16 ----------
// 64-row Q tiles: grid = 32 bh * 32 qt2, HEAVY-FIRST (qt2 descending with blockIdx) so the
// long-running diagonal blocks dispatch first and short blocks backfill (kills the tail
// that held R4 at 6.2% occupancy). Each of 4 waves owns 16 t-columns; Q-frags loaded
// directly from global (8 KB/block, one-shot). S^T = K·Q^T; C-layout of S^T == B-operand
// layout of 16x16x16 => P feeds PV (O^T = V^T·P^T) straight from registers.
__global__ __launch_bounds__(256) void attn_fused(const u16* __restrict__ qf16,
                                                  const u16* __restrict__ kf16,
                                                  const u16* __restrict__ vtf,
                                                  u16* __restrict__ Ob) {
  __shared__ u16 Ks[128 * 64];              // K tile (s,d) f16, chunk-swizzled
  __shared__ u16 Vts[64 * 128];             // V^T tile (d,s) f16, chunk-swizzled
  const int tid = threadIdx.x;
  const int lane = tid & 63, wave = tid >> 6;
  const int quad = lane >> 4, l16 = lane & 15;
  const int qh2 = quad >> 1, ql2 = (quad & 1) * 4;  // frag sub-chunk addressing
  const int qt2 = 31 - (blockIdx.x >> 5);   // heavy-first: qt2=31 blocks launch first
  const int bh  = blockIdx.x & 31;
  const int t0  = qt2 * 64;
  const int tw  = t0 + wave * 16;           // this wave's 16 t-columns

  // Q B-frags straight from global: B[k=d][n=t], lane: t=tw+l16, d=kc*16+quad*4+j
  const u16* Qg = qf16 + ((size_t)bh * T_SEQ + tw) * HD;
  half4 qfrag[4];
#pragma unroll
  for (int kc = 0; kc < 4; kc++)
    qfrag[kc] = *(const half4*)&Qg[(size_t)l16 * HD + kc * 16 + quad * 4];

  floatx4 oacc[4] = {};                     // O^T tiles [dt]
  float mrow = -1e30f, lrow = 0.f;
  const int nkt = (qt2 >> 1) + 1;           // 128-wide k-tiles (last one holds diagonal)

  for (int kt = 0; kt < nkt; kt++) {
    __syncthreads();                        // prev compute done reading Ks/Vts
    const size_t koff = ((size_t)bh * T_SEQ + kt * 128) * HD;
    const u16* Vg = vtf + (size_t)bh * HD * T_SEQ + kt * 128;
#pragma unroll
    for (int j = 0; j < 4; j++) {
      int t2 = j * 256 + tid;
      int r = t2 >> 3, c = t2 & 7;
      gld16(kf16 + koff + r * HD + (c ^ (r & 7)) * 8, &Ks[t2 * 8]);
    }
#pragma unroll
    for (int j = 0; j < 4; j++) {
      int t2 = j * 256 + tid;
      int r = t2 >> 4, c = t2 & 15;
      gld16(Vg + (size_t)r * T_SEQ + (c ^ (r & 15)) * 8, &Vts[t2 * 8]);
    }
    __syncthreads();                        // staging landed

    // S^T = K·Q^T : A=K (m=s), B=Q^T frags
    floatx4 sacc[8] = {};
#pragma unroll
    for (int kc = 0; kc < 4; kc++)
#pragma unroll
      for (int st = 0; st < 8; st++) {
        int srow = st * 16 + l16;
        half4 ak = *(const half4*)&Ks[srow * 64 + (((kc * 2 + qh2) ^ (srow & 7)) * 8) + ql2];
        sacc[st] = __builtin_amdgcn_mfma_f32_16x16x16f16(ak, qfrag[kc], sacc[st], 0, 0, 0);
      }
    if (kt == nkt - 1) {                    // diagonal tile: causal mask s<=t
      int tg = tw + l16;
#pragma unroll
      for (int st = 0; st < 8; st++) {
        int sg = kt * 128 + st * 16 + quad * 4;
#pragma unroll
        for (int r = 0; r < 4; r++)
          if (sg + r > tg) sacc[st][r] = -1e30f;
      }
    }
    // online softmax per t-column (base-2; scale folded into q)
    {
      floatx4 vm = sacc[0];
#pragma unroll
      for (int st = 1; st < 8; st++) {
        vm[0] = fmaxf(vm[0], sacc[st][0]); vm[1] = fmaxf(vm[1], sacc[st][1]);
        vm[2] = fmaxf(vm[2], sacc[st][2]); vm[3] = fmaxf(vm[3], sacc[st][3]);
      }
      float mx = fmaxf(fmaxf(vm[0], vm[1]), fmaxf(vm[2], vm[3]));
      mx = fmaxf(mx, __shfl_xor(mx, 16));
      mx = fmaxf(mx, __shfl_xor(mx, 32));
      float mnew = fmaxf(mrow, mx);
      float alpha = exp2f(mrow - mnew);
      mrow = mnew;
      floatx4 vs = {0.f, 0.f, 0.f, 0.f};
#pragma unroll
      for (int st = 0; st < 8; st++) {
#pragma unroll
        for (int r = 0; r < 4; r++) sacc[st][r] = exp2f(sacc[st][r] - mnew);
        vs += sacc[st];
      }
      float rs = (vs[0] + vs[1]) + (vs[2] + vs[3]);
      rs += __shfl_xor(rs, 16);
      rs += __shfl_xor(rs, 32);
      lrow = lrow * alpha + rs;
#pragma unroll
      for (int dt = 0; dt < 4; dt++) oacc[dt] *= alpha;   // alpha lane-uniform per t-col
    }
    // O^T += V^T · P^T : P^T B-frags straight from sacc registers (packed cvt)
#pragma unroll
    for (int st = 0; st < 8; st++) {
      union { unsigned u[2]; half4 h; } pc;
      pc.u[0] = pk2h(sacc[st][0], sacc[st][1]);
      pc.u[1] = pk2h(sacc[st][2], sacc[st][3]);
      half4 bp = pc.h;
#pragma unroll
      for (int dt = 0; dt < 4; dt++) {
        int drow = dt * 16 + l16;
        half4 av = *(const half4*)&Vts[drow * 128 + (((st * 2 + qh2) ^ (drow & 15)) * 8) + ql2];
        oacc[dt] = __builtin_amdgcn_mfma_f32_16x16x16f16(av, bp, oacc[dt], 0, 0, 0);
      }
    }
  }
  // epilogue: O[t][d] = oacc^T / l ; write bf16 (B,T,C)
  const int b = bh >> 4, h = bh & 15;
  {
    int t = tw + l16;
    float invl = 1.f / lrow;
#pragma unroll
    for (int dt = 0; dt < 4; dt++) {
      int d0 = dt * 16 + quad * 4;
      ushort4 o;
      o.x = f2bf(oacc[dt][0] * invl);
      o.y = f2bf(oacc[dt][1] * invl);
      o.z = f2bf(oacc[dt][2] * invl);
      o.w = f2bf(oacc[dt][3] * invl);
      *(ushort4*)&Ob[((size_t)(b * T_SEQ) + t) * CDIM + h * HD + d0] = o;
    }
  }
}

extern "C" void kernel_launch(void* const* d_in, const int* in_sizes, int n_in,
                              void* d_out, int out_size, void* d_ws, size_t ws_size,
                              hipStream_t stream) {
  const float* x     = (const float*)d_in[0];
  const float* w_qkv = (const float*)d_in[2];
  const float* w_out = (const float*)d_in[3];
  float* out    = (float*)d_out;                       // (B,T,C) fp32
  float* kt_out = out + (size_t)BDIM * T_SEQ * CDIM;   // (B,H,T,64) fp32
  float* vt_out = kt_out + (size_t)BDIM * T_SEQ * CDIM;

  // workspace layout (64 MB, with aliasing)
  const size_t F = (size_t)4194304;     // 4M elems = 4096x1024
  char* base = (char*)d_ws;
  u16* xb   = (u16*)base;                        // [0,8M)   dead after gemm_qkv
  u16* wqT  = xb + F;                            // [8,14M)  dead after gemm_qkv
  u16* woT  = wqT + (size_t)3145728;             // [14,16M) lives to end
  u16* qkvb = woT + (size_t)1048576;             // [16,40M) dead after v_pack
  u16* qf16 = qkvb + (size_t)3 * F;              // [40,48M)
  u16* kf16 = qf16 + F;                          // [48,56M)
  u16* vtf  = (u16*)base;                        // alias xb  [0,8M)
  u16* Ob   = kf16 + F;                          // [56,64M)

  cast_bf16<<<4096, 256, 0, stream>>>(x, xb, 1048576);
  transpose_cast<<<dim3(96, 32), dim3(32, 8), 0, stream>>>(w_qkv, wqT, 1024, 3072);
  transpose_cast<<<dim3(32, 32), dim3(32, 8), 0, stream>>>(w_out, woT, 1024, 1024);
  gemm_bt<false><<<dim3(32, 24), 256, 0, stream>>>(xb, wqT, (float*)nullptr, qkvb, 4096, 3072, 1024);
  rope_qk<<<16384, 256, 0, stream>>>(qkvb, qf16, kf16, kt_out);
  v_pack<<<1024, 256, 0, stream>>>(qkvb, vt_out, vtf);
  attn_fused<<<1024, 256, 0, stream>>>(qf16, kf16, vtf, Ob);
  gemm_bt<true><<<dim3(32, 8), 256, 0, stream>>>(Ob, woT, out, (u16*)nullptr, 4096, 1024, 1024);
}

// Round 7
// 224.699 us; speedup vs baseline: 1.8241x; 1.0424x over previous
//
#include <hip/hip_runtime.h>

// Problem constants (B=2, T=2048, C=1024, H=16, hd=64)
#define T_SEQ 2048
#define NH    16
#define HD    64
#define CDIM  1024
#define BDIM  2

using floatx4 = __attribute__((ext_vector_type(4))) float;
using bf16x8  = __attribute__((ext_vector_type(8))) __bf16;
using half4   = __attribute__((ext_vector_type(4))) _Float16;
using half8   = __attribute__((ext_vector_type(8))) _Float16;
typedef unsigned short u16;

__device__ __forceinline__ u16 f2bf(float f) {
  unsigned int u = __float_as_uint(f);
  u += 0x7fffu + ((u >> 16) & 1u);          // RNE
  return (u16)(u >> 16);
}
__device__ __forceinline__ float bf2f(u16 h) {
  return __uint_as_float(((unsigned int)h) << 16);
}
__device__ __forceinline__ u16 f2h(float f) {
  union { _Float16 h; u16 u; } c; c.h = (_Float16)f; return c.u;
}
// packed f32x2 -> f16x2 (RTZ)
__device__ __forceinline__ unsigned pk2h(float a, float b) {
  return __builtin_bit_cast(unsigned, __builtin_amdgcn_cvt_pkrtz(a, b));
}
// async global->LDS, 16B/lane; LDS dest must be wave-uniform base + lane*16.
__device__ __forceinline__ void gld16(const void* g, const void* l) {
  __builtin_amdgcn_global_load_lds(
      (const __attribute__((address_space(1))) unsigned int*)(unsigned long long)g,
      (__attribute__((address_space(3))) unsigned int*)(unsigned int)(unsigned long long)l,
      16, 0, 0);
}

// ---------------- fused preprocessing: x cast + both weight transposes ----------------
__global__ __launch_bounds__(256) void preproc(const float* __restrict__ x,
                                               const float* __restrict__ w_qkv,
                                               const float* __restrict__ w_out,
                                               u16* __restrict__ xb,
                                               u16* __restrict__ wqT,
                                               u16* __restrict__ woT) {
  __shared__ float tile[32][33];
  int blk = blockIdx.x, tid = threadIdx.x;
  if (blk < 4096) {                         // cast x -> bf16 (4M floats, float4 per thread)
    int i = blk * 256 + tid;
    float4 v = ((const float4*)x)[i];
    ushort4 o;
    o.x = f2bf(v.x); o.y = f2bf(v.y); o.z = f2bf(v.z); o.w = f2bf(v.w);
    ((ushort4*)xb)[i] = o;
    return;
  }
  const float* W; u16* WT; int K, N, bx, by;
  if (blk < 4096 + 3072) {                  // w_qkv (1024,3072) -> wqT (3072,1024)
    int idx = blk - 4096; W = w_qkv; WT = wqT; K = 1024; N = 3072;
    bx = idx % 96; by = idx / 96;
  } else {                                  // w_out (1024,1024) -> woT
    int idx = blk - 7168; W = w_out; WT = woT; K = 1024; N = 1024;
    bx = idx & 31; by = idx >> 5;
  }
  int n0 = bx * 32, k0 = by * 32;
  int tx = tid & 31, ty = tid >> 5;         // (32,8)
#pragma unroll
  for (int i = 0; i < 32; i += 8)
    tile[ty + i][tx] = W[(size_t)(k0 + ty + i) * N + n0 + tx];
  __syncthreads();
#pragma unroll
  for (int i = 0; i < 32; i += 8)
    WT[(size_t)(n0 + ty + i) * K + k0 + tx] = f2bf(tile[tx][ty + i]);
}

// ---------------- single-bf16 GEMM (m97 structure): C(M,N) = A(M,K)*BT(N,K)^T ----------
template <bool OUT_F32>
__global__ __launch_bounds__(256) void gemm_bt(const u16* __restrict__ A,
                                               const u16* __restrict__ BT,
                                               float* __restrict__ Cf,
                                               u16* __restrict__ Cb,
                                               int M, int N, int K) {
  __shared__ u16 As[128 * 32];
  __shared__ u16 Bs[128 * 32];
  const int tid  = threadIdx.x;
  const int lane = tid & 63, wave = tid >> 6;
  const int quad = lane >> 4, l16 = lane & 15;
  const int wm = (wave & 1) * 64, wn = (wave >> 1) * 64;
  const int row0 = blockIdx.x * 128, col0 = blockIdx.y * 128;
  const int srow = tid >> 2;                       // staging row 0..63
  const int sc   = tid & 3;                        // chunk 0..3 (8 elems)
  const int sgc  = (sc ^ ((srow >> 1) & 3)) * 8;   // swizzled source chunk
  floatx4 acc[4][4] = {};
  for (int k0 = 0; k0 < K; k0 += 32) {
    __syncthreads();
    gld16(A  + (size_t)(row0 + srow     ) * K + k0 + sgc, &As[srow * 32 + sc * 8]);
    gld16(A  + (size_t)(row0 + srow + 64) * K + k0 + sgc, &As[(srow + 64) * 32 + sc * 8]);
    gld16(BT + (size_t)(col0 + srow     ) * K + k0 + sgc, &Bs[srow * 32 + sc * 8]);
    gld16(BT + (size_t)(col0 + srow + 64) * K + k0 + sgc, &Bs[(srow + 64) * 32 + sc * 8]);
    __syncthreads();
    bf16x8 af[4], bfv[4];
#pragma unroll
    for (int mt = 0; mt < 4; mt++) {
      int r = wm + mt * 16 + l16;
      af[mt] = *(const bf16x8*)&As[r * 32 + (quad ^ ((r >> 1) & 3)) * 8];
    }
#pragma unroll
    for (int nt = 0; nt < 4; nt++) {
      int r = wn + nt * 16 + l16;
      bfv[nt] = *(const bf16x8*)&Bs[r * 32 + (quad ^ ((r >> 1) & 3)) * 8];
    }
#pragma unroll
    for (int mt = 0; mt < 4; mt++)
#pragma unroll
      for (int nt = 0; nt < 4; nt++)
        acc[mt][nt] = __builtin_amdgcn_mfma_f32_16x16x32_bf16(af[mt], bfv[nt], acc[mt][nt], 0, 0, 0);
  }
  // C/D layout: col = lane&15, row = quad*4 + reg
#pragma unroll
  for (int mt = 0; mt < 4; mt++)
#pragma unroll
    for (int nt = 0; nt < 4; nt++)
#pragma unroll
      for (int r = 0; r < 4; r++) {
        int row = row0 + wm + mt * 16 + quad * 4 + r;
        int col = col0 + wn + nt * 16 + l16;
        float v = acc[mt][nt][r];
        if (OUT_F32) Cf[(size_t)row * N + col] = v;
        else         Cb[(size_t)row * N + col] = f2bf(v);
      }
}

// ---------------- fused RoPE (q,k) + V pack ----------------
__global__ __launch_bounds__(256) void rope_vpack(const u16* __restrict__ qkv,
                                                  u16* __restrict__ qf16,
                                                  u16* __restrict__ kf16,
                                                  float* __restrict__ kt_out,
                                                  float* __restrict__ vt_out,
                                                  u16* __restrict__ vtf) {
  int blk = blockIdx.x;
  if (blk < 16384) {                        // RoPE on q,k
    int gid = blk * 4 + (threadIdx.x >> 6); // (b,h,t) row index
    int d   = threadIdx.x & 63;
    int t   = gid & (T_SEQ - 1);
    int h   = (gid >> 11) & 15;
    int b   = gid >> 15;
    const u16* qrow = qkv + ((size_t)(b * T_SEQ + t)) * 3072 + h * 64;
    int i = d & 31;
    unsigned int qp = *(const unsigned int*)(qrow + 2 * i);
    unsigned int kp = *(const unsigned int*)(qrow + 1024 + 2 * i);
    float q1 = bf2f((u16)qp), q2 = bf2f((u16)(qp >> 16));
    float k1 = bf2f((u16)kp), k2 = bf2f((u16)(kp >> 16));
    float inv = expf((float)i * -0.28782313662425572f);  // 10000^(-i/32)
    float ang = (float)t * inv;
    float sn = sinf(ang), cs = cosf(ang);
    float qv = (d < 32) ? (q1 * cs - q2 * sn) : (q1 * sn + q2 * cs);
    float kv = (d < 32) ? (k1 * cs - k2 * sn) : (k1 * sn + k2 * cs);
    size_t o = (size_t)gid * 64 + d;
    qf16[o] = f2h(qv * 0.18033688011112042f);   // 0.125 * log2(e): base-2 softmax
    kf16[o] = f2h(kv);
    kt_out[o] = kv;
    return;
  }
  // V: v_t fp32 output + V^T f16 (BH,64,T)
  __shared__ float tile[64][65];
  int b2 = blk - 16384;
  int t0 = (b2 & 31) * 64;
  int bh = b2 >> 5;
  int b = bh >> 4, h = bh & 15;
  int tx = threadIdx.x & 63, ty = threadIdx.x >> 6;
#pragma unroll
  for (int i = ty; i < 64; i += 4) {
    float v = bf2f(qkv[((size_t)(b * T_SEQ + t0 + i)) * 3072 + 2048 + h * 64 + tx]);
    tile[i][tx] = v;
    vt_out[((size_t)bh * T_SEQ + t0 + i) * 64 + tx] = v;
  }
  __syncthreads();
#pragma unroll
  for (int i = ty; i < 64; i += 4)
    vtf[((size_t)bh * 64 + i) * T_SEQ + t0 + tx] = f2h(tile[tx][i]);
}

// ---------------- fused causal flash attention, S^T orientation ----------
// PAIRED STRIPS for perfect balance: block (bh, j) processes strips qt2 = 31-j then j.
// tiles(qt2) = (qt2>>1)+1  =>  per-block total = 16 or 17 k-tiles for EVERY block.
// Grid 512 = 2 blocks/CU, all resident, zero tail. Each of 4 waves owns 16 t-columns.
// QK via 16x16x32 f16 (16 MFMA + 16 b128 LDS reads/tile); S^T C-layout == B-operand
// layout of 16x16x16 => P feeds PV (O^T = V^T·P^T) straight from registers.
__global__ __launch_bounds__(256) void attn_fused(const u16* __restrict__ qf16,
                                                  const u16* __restrict__ kf16,
                                                  const u16* __restrict__ vtf,
                                                  u16* __restrict__ Ob) {
  __shared__ u16 Ks[128 * 64];              // K tile (s,d) f16, chunk-swizzled
  __shared__ u16 Vts[64 * 128];             // V^T tile (d,s) f16, chunk-swizzled
  const int tid = threadIdx.x;
  const int lane = tid & 63, wave = tid >> 6;
  const int quad = lane >> 4, l16 = lane & 15;
  const int qh2 = quad >> 1, ql2 = (quad & 1) * 4;
  const int j   = blockIdx.x >> 5;          // pair index 0..15
  const int bh  = blockIdx.x & 31;
  const int b = bh >> 4, h = bh & 15;

#pragma unroll 1
  for (int s2 = 0; s2 < 2; s2++) {
    const int qt2 = s2 ? j : (31 - j);      // heavy strip first (K/V reuse descending)
    const int tw  = qt2 * 64 + wave * 16;   // this wave's 16 t-columns
    // Q B-frags (16x16x32 layout) straight from global: t=tw+l16, d=kc*32+quad*8+j8
    const u16* Qg = qf16 + ((size_t)bh * T_SEQ + tw) * HD;
    half8 qfrag[2];
#pragma unroll
    for (int kc = 0; kc < 2; kc++)
      qfrag[kc] = *(const half8*)&Qg[(size_t)l16 * HD + kc * 32 + quad * 8];

    floatx4 oacc[4] = {};                   // O^T tiles [dt]
    float mrow = -1e30f, lrow = 0.f;
    const int nkt = (qt2 >> 1) + 1;         // 128-wide k-tiles (last holds diagonal)

    for (int kt = 0; kt < nkt; kt++) {
      __syncthreads();                      // prev compute done reading Ks/Vts
      const size_t koff = ((size_t)bh * T_SEQ + kt * 128) * HD;
      const u16* Vg = vtf + (size_t)bh * HD * T_SEQ + kt * 128;
#pragma unroll
      for (int jj = 0; jj < 4; jj++) {
        int t2 = jj * 256 + tid;
        int r = t2 >> 3, c = t2 & 7;
        gld16(kf16 + koff + r * HD + (c ^ (r & 7)) * 8, &Ks[t2 * 8]);
      }
#pragma unroll
      for (int jj = 0; jj < 4; jj++) {
        int t2 = jj * 256 + tid;
        int r = t2 >> 4, c = t2 & 15;
        gld16(Vg + (size_t)r * T_SEQ + (c ^ (r & 15)) * 8, &Vts[t2 * 8]);
      }
      __syncthreads();                      // staging landed

      // S^T = K·Q^T : A=K (m=s, k=d chunks of 8), B=Q^T frags
      floatx4 sacc[8] = {};
#pragma unroll
      for (int kc = 0; kc < 2; kc++)
#pragma unroll
        for (int st = 0; st < 8; st++) {
          int srow = st * 16 + l16;
          half8 ak = *(const half8*)&Ks[srow * 64 + (((kc * 4 + quad) ^ (srow & 7)) * 8)];
          sacc[st] = __builtin_amdgcn_mfma_f32_16x16x32_f16(ak, qfrag[kc], sacc[st], 0, 0, 0);
        }
      if (kt == nkt - 1) {                  // diagonal tile: causal mask s<=t
        int tg = tw + l16;
#pragma unroll
        for (int st = 0; st < 8; st++) {
          int sg = kt * 128 + st * 16 + quad * 4;
#pragma unroll
          for (int r = 0; r < 4; r++)
            if (sg + r > tg) sacc[st][r] = -1e30f;
        }
      }
      // online softmax per t-column (base-2; scale folded into q)
      {
        floatx4 vm = sacc[0];
#pragma unroll
        for (int st = 1; st < 8; st++) {
          vm[0] = fmaxf(vm[0], sacc[st][0]); vm[1] = fmaxf(vm[1], sacc[st][1]);
          vm[2] = fmaxf(vm[2], sacc[st][2]); vm[3] = fmaxf(vm[3], sacc[st][3]);
        }
        float mx = fmaxf(fmaxf(vm[0], vm[1]), fmaxf(vm[2], vm[3]));
        mx = fmaxf(mx, __shfl_xor(mx, 16));
        mx = fmaxf(mx, __shfl_xor(mx, 32));
        float mnew = fmaxf(mrow, mx);
        float alpha = exp2f(mrow - mnew);
        mrow = mnew;
        floatx4 vs = {0.f, 0.f, 0.f, 0.f};
#pragma unroll
        for (int st = 0; st < 8; st++) {
#pragma unroll
          for (int r = 0; r < 4; r++) sacc[st][r] = exp2f(sacc[st][r] - mnew);
          vs += sacc[st];
        }
        float rs = (vs[0] + vs[1]) + (vs[2] + vs[3]);
        rs += __shfl_xor(rs, 16);
        rs += __shfl_xor(rs, 32);
        lrow = lrow * alpha + rs;
#pragma unroll
        for (int dt = 0; dt < 4; dt++) oacc[dt] *= alpha;
      }
      // O^T += V^T · P^T : P^T B-frags straight from sacc registers (packed cvt)
#pragma unroll
      for (int st = 0; st < 8; st++) {
        union { unsigned u[2]; half4 h; } pc;
        pc.u[0] = pk2h(sacc[st][0], sacc[st][1]);
        pc.u[1] = pk2h(sacc[st][2], sacc[st][3]);
        half4 bp = pc.h;
#pragma unroll
        for (int dt = 0; dt < 4; dt++) {
          int drow = dt * 16 + l16;
          half4 av = *(const half4*)&Vts[drow * 128 + (((st * 2 + qh2) ^ (drow & 15)) * 8) + ql2];
          oacc[dt] = __builtin_amdgcn_mfma_f32_16x16x16f16(av, bp, oacc[dt], 0, 0, 0);
        }
      }
    }
    // epilogue: O[t][d] = oacc^T / l ; write bf16 (B,T,C)
    {
      int t = tw + l16;
      float invl = 1.f / lrow;
#pragma unroll
      for (int dt = 0; dt < 4; dt++) {
        int d0 = dt * 16 + quad * 4;
        ushort4 o;
        o.x = f2bf(oacc[dt][0] * invl);
        o.y = f2bf(oacc[dt][1] * invl);
        o.z = f2bf(oacc[dt][2] * invl);
        o.w = f2bf(oacc[dt][3] * invl);
        *(ushort4*)&Ob[((size_t)(b * T_SEQ) + t) * CDIM + h * HD + d0] = o;
      }
    }
  }
}

extern "C" void kernel_launch(void* const* d_in, const int* in_sizes, int n_in,
                              void* d_out, int out_size, void* d_ws, size_t ws_size,
                              hipStream_t stream) {
  const float* x     = (const float*)d_in[0];
  const float* w_qkv = (const float*)d_in[2];
  const float* w_out = (const float*)d_in[3];
  float* out    = (float*)d_out;                       // (B,T,C) fp32
  float* kt_out = out + (size_t)BDIM * T_SEQ * CDIM;   // (B,H,T,64) fp32
  float* vt_out = kt_out + (size_t)BDIM * T_SEQ * CDIM;

  // workspace layout (64 MB, with aliasing)
  const size_t F = (size_t)4194304;     // 4M elems = 4096x1024
  char* base = (char*)d_ws;
  u16* xb   = (u16*)base;                        // [0,8M)   dead after gemm_qkv
  u16* wqT  = xb + F;                            // [8,14M)  dead after gemm_qkv
  u16* woT  = wqT + (size_t)3145728;             // [14,16M) lives to end
  u16* qkvb = woT + (size_t)1048576;             // [16,40M) dead after rope_vpack
  u16* qf16 = qkvb + (size_t)3 * F;              // [40,48M)
  u16* kf16 = qf16 + F;                          // [48,56M)
  u16* vtf  = (u16*)base;                        // alias xb  [0,8M)
  u16* Ob   = kf16 + F;                          // [56,64M)

  preproc<<<8192, 256, 0, stream>>>(x, w_qkv, w_out, xb, wqT, woT);
  gemm_bt<false><<<dim3(32, 24), 256, 0, stream>>>(xb, wqT, (float*)nullptr, qkvb, 4096, 3072, 1024);
  rope_vpack<<<17408, 256, 0, stream>>>(qkvb, qf16, kf16, kt_out, vt_out, vtf);
  attn_fused<<<512, 256, 0, stream>>>(qf16, kf16, vtf, Ob);
  gemm_bt<true><<<dim3(32, 8), 256, 0, stream>>>(Ob, woT, out, (u16*)nullptr, 4096, 1024, 1024);
}